// Round 2
// baseline (681.229 us; speedup 1.0000x reference)
//
#include <hip/hip_runtime.h>
#include <hip/hip_bf16.h>

// ScaledDotProductAttention: B=8,H=16,S=512,D=512, fp32 in/out.
// out[b,h,s,d] = sum_t softmax_t(Q.K^T/sqrt(D))[s,t] * V[b,h,d,t]   (scores @ V^T)
//
// v3: 1024 threads (16 waves = 4/SIMD for TLP) + 2-deep register prefetch
//     (rvA/rvB ping-pong; chunk c+2 issued at step c, written at step c+1).
//     Wave = 16 rows x 128 cols (8 frags). XOR-swizzled smB kept from v2.

typedef __attribute__((ext_vector_type(4))) float floatx4;
typedef __attribute__((ext_vector_type(8))) short shortx8;

#define SEQ 512
#define DIM 512
#define MQ   64          // Q rows per workgroup
#define NTH 1024         // threads per block (16 waves)
#define KCH  32          // k-chunk depth (one 16x16x32 MFMA step)
#define LDA 520          // smA row stride in bf16 elems
#define LDBS 32          // smB row stride in bf16 elems, UNPADDED + XOR swizzle

__device__ __forceinline__ unsigned short f2bf(float f) {
  union { __hip_bfloat16 b; unsigned short u; } cv;
  cv.b = __float2bfloat16(f);
  return cv.u;
}

__device__ __forceinline__ uint2 cvt4(float4 f) {
  union { __hip_bfloat162 b; unsigned int u; } lo, hi;
  lo.b = __float22bfloat162_rn(make_float2(f.x, f.y));
  hi.b = __float22bfloat162_rn(make_float2(f.z, f.w));
  uint2 r; r.x = lo.u; r.y = hi.u;
  return r;
}

__global__ __launch_bounds__(NTH, 4)
void sdpa_kernel(const float* __restrict__ q, const float* __restrict__ k,
                 const float* __restrict__ v, float* __restrict__ out) {
  __shared__ unsigned short smA[MQ * LDA];        // Q tile (bf16), later P tile
  __shared__ unsigned short smB[2][SEQ * LDBS];   // double-buffered K/V chunk staging
  __shared__ float red[MQ][8];                    // [0..3]=rowmax qtrs, [4..7]=rowsum

  const int tid  = threadIdx.x;
  const int lane = tid & 63;
  const int wid  = tid >> 6;       // 0..15
  const int strip = wid >> 2;      // 0..3 : 16-row strip
  const int qcol  = wid & 3;       // 0..3 : 128-col quarter
  const int l15  = lane & 15;
  const int quad = lane >> 4;      // 0..3

  // XCD-aware swizzle: all 8 q-tiles of a head land on the same XCD (id%8).
  const int id = blockIdx.x;
  const int cx = id & 7;
  const int g  = id >> 3;
  const int qtile = g & 7;
  const int head  = ((g >> 3) << 3) | cx;

  const size_t hb = (size_t)head * (SEQ * DIM);
  const float* qh = q + hb + (size_t)qtile * MQ * DIM;
  const float* kh = k + hb;
  const float* vh = v + hb;
  float*       oh = out + hb + (size_t)qtile * MQ * DIM;

  const float scale = 0.044194173824159216f;  // 1/sqrt(512), folded into Q

  // ---- per-thread staging geometry ----
  // chunk = 512 rows x 32 floats = 4096 float4; 1024 thr -> 4 per thread.
  // flat = i*1024+tid -> row = i*128 + (tid>>3), 8B-unit c4 = tid&7.
  // swizzled physical unit = c4 ^ (row&6); row&6 == r0&6 (i*128 % 8 == 0).
  const int r0 = tid >> 3;                              // 0..127
  const int c4 = tid & 7;
  const int sldx = r0 * LDBS + ((c4 ^ (r0 & 6)) << 2);  // swizzled short offset

  float4 rvA[4], rvB[4];

  // ---- issue chunk 0 (K cols 0..31) loads; hide under Q staging ----
  #pragma unroll
  for (int i = 0; i < 4; ++i)
    rvA[i] = *(const float4*)(kh + (size_t)(i * 128 + r0) * DIM + (c4 << 2));

  // ---- Phase 0: load Q tile (64x512 fp32), scale, convert, -> smA ----
  {
    const int qc  = tid & 127;       // float4 index within row
    const int qr0 = tid >> 7;        // 0..7
    #pragma unroll
    for (int i = 0; i < 8; ++i) {
      int row = i * 8 + qr0;
      float4 f = *(const float4*)(qh + (size_t)row * DIM + (qc << 2));
      f.x *= scale; f.y *= scale; f.z *= scale; f.w *= scale;
      *(uint2*)(&smA[row * LDA + (qc << 2)]) = cvt4(f);
    }
  }

  // ---- write chunk 0 into smB[0]; issue chunk 1 into rvA ----
  #pragma unroll
  for (int i = 0; i < 4; ++i)
    *(uint2*)(&smB[0][i * 128 * LDBS + sldx]) = cvt4(rvA[i]);
  #pragma unroll
  for (int i = 0; i < 4; ++i)
    rvA[i] = *(const float4*)(kh + KCH + (size_t)(i * 128 + r0) * DIM + (c4 << 2));
  __syncthreads();

  floatx4 acc[8];
  #pragma unroll
  for (int i = 0; i < 8; ++i) acc[i] = (floatx4)(0.0f);

  const int arow = (strip * 16 + l15) * LDA + quad * 8;   // + chunk*KCH
  const int bu = (((quad << 1) ^ (l15 & 6)) << 2);        // swizzled short off
  int cur = 0;

  // One pipelined step: MFMA chunk cc from smB[cur]; RD holds chunk cc+1
  // (written to smB[cur^1] after the MFMAs); WR receives chunk cc+2 (issued
  // first so its latency spans a full step + this step's MFMA/LDS work).
  // Global chunk index: 0..15 = K k-chunks, 16..31 = V t-chunks.
  #define STEP(cc, RD, WR)                                                      \
  {                                                                             \
    if ((cc) + 2 < 32) {                                                        \
      const float* s_ = ((cc) + 2 < 16) ? (kh + ((cc) + 2) * KCH)               \
                                        : (vh + ((cc) - 14) * KCH);             \
      _Pragma("unroll")                                                         \
      for (int i = 0; i < 4; ++i)                                               \
        WR[i] = *(const float4*)(s_ + (size_t)(i * 128 + r0) * DIM + (c4 << 2));\
    }                                                                           \
    shortx8 a_ = *(const shortx8*)(&smA[arow + ((cc) & 15) * KCH]);             \
    _Pragma("unroll")                                                           \
    for (int t_ = 0; t_ < 8; ++t_) {                                            \
      int brow_ = qcol * 128 + t_ * 16 + l15;                                   \
      shortx8 b_ = *(const shortx8*)(&smB[cur][brow_ * LDBS + bu]);             \
      acc[t_] = __builtin_amdgcn_mfma_f32_16x16x32_bf16(a_, b_, acc[t_], 0,0,0);\
    }                                                                           \
    if ((cc) + 1 < 32) {                                                        \
      __builtin_amdgcn_sched_barrier(0); /* keep vm-waits below the MFMAs */    \
      _Pragma("unroll")                                                         \
      for (int i = 0; i < 4; ++i)                                               \
        *(uint2*)(&smB[cur ^ 1][i * 128 * LDBS + sldx]) = cvt4(RD[i]);          \
      __syncthreads();                                                          \
      cur ^= 1;                                                                 \
    }                                                                           \
  }

  // ---- Phase 1: logits = scaledQ . K^T (chunks 0..15) ----
  for (int kc = 0; kc < 16; kc += 2) {
    STEP(kc,     rvA, rvB);
    STEP(kc + 1, rvB, rvA);
  }
  // smB[cur] now holds V chunk 0 (chunk 16); rvA holds chunk 17 (in flight
  // across the whole softmax phase).

  // ---- Phase 2: softmax over full 512-wide rows (fp32) ----
  // D-layout: (ct,r) -> row strip*16 + quad*4 + r, col qcol*128 + ct*16 + l15
  float mx[4], sm[4];
  #pragma unroll
  for (int r = 0; r < 4; ++r) mx[r] = -1e30f;
  #pragma unroll
  for (int ct = 0; ct < 8; ++ct)
    #pragma unroll
    for (int r = 0; r < 4; ++r) mx[r] = fmaxf(mx[r], acc[ct][r]);
  #pragma unroll
  for (int off = 8; off >= 1; off >>= 1)
    #pragma unroll
    for (int r = 0; r < 4; ++r) mx[r] = fmaxf(mx[r], __shfl_xor(mx[r], off, 16));

  const int row0 = strip * 16 + quad * 4;
  if (l15 == 0) {
    #pragma unroll
    for (int r = 0; r < 4; ++r) red[row0 + r][qcol] = mx[r];
  }
  __syncthreads();
  #pragma unroll
  for (int r = 0; r < 4; ++r) {
    mx[r] = fmaxf(fmaxf(red[row0 + r][0], red[row0 + r][1]),
                  fmaxf(red[row0 + r][2], red[row0 + r][3]));
    sm[r] = 0.0f;
  }
  #pragma unroll
  for (int ct = 0; ct < 8; ++ct)
    #pragma unroll
    for (int r = 0; r < 4; ++r) {
      float e = __expf(acc[ct][r] - mx[r]);
      acc[ct][r] = e;
      sm[r] += e;
    }
  #pragma unroll
  for (int off = 8; off >= 1; off >>= 1)
    #pragma unroll
    for (int r = 0; r < 4; ++r) sm[r] += __shfl_xor(sm[r], off, 16);
  if (l15 == 0) {
    #pragma unroll
    for (int r = 0; r < 4; ++r) red[row0 + r][4 + qcol] = sm[r];
  }
  __syncthreads();
  float inv[4];
  #pragma unroll
  for (int r = 0; r < 4; ++r)
    inv[r] = 1.0f / (red[row0 + r][4] + red[row0 + r][5] +
                     red[row0 + r][6] + red[row0 + r][7]);

  // write normalized P (bf16) into smA (Q is dead; all Q reads completed)
  #pragma unroll
  for (int ct = 0; ct < 8; ++ct) {
    int t = qcol * 128 + ct * 16 + l15;
    #pragma unroll
    for (int r = 0; r < 4; ++r) {
      smA[(row0 + r) * LDA + t] = f2bf(acc[ct][r] * inv[r]);
    }
  }
  __syncthreads();   // P visible to all waves before GEMM2 a-frag reads

  // ---- Phase 3: O = P . V^T (chunks 16..31; pipeline continues) ----
  #pragma unroll
  for (int i = 0; i < 8; ++i) acc[i] = (floatx4)(0.0f);

  for (int tc = 16; tc < 32; tc += 2) {
    STEP(tc,     rvA, rvB);
    STEP(tc + 1, rvB, rvA);
  }

  // ---- Epilogue: store O (fp32) ----
  #pragma unroll
  for (int dt = 0; dt < 8; ++dt) {
    int col = qcol * 128 + dt * 16 + l15;
    #pragma unroll
    for (int r = 0; r < 4; ++r) {
      oh[(row0 + r) * DIM + col] = acc[dt][r];
    }
  }
}

extern "C" void kernel_launch(void* const* d_in, const int* in_sizes, int n_in,
                              void* d_out, int out_size, void* d_ws, size_t ws_size,
                              hipStream_t stream) {
  const float* q = (const float*)d_in[0];
  const float* k = (const float*)d_in[1];
  const float* v = (const float*)d_in[2];
  float* out = (float*)d_out;
  (void)in_sizes; (void)n_in; (void)out_size; (void)d_ws; (void)ws_size;
  sdpa_kernel<<<dim3(8 * 16 * (SEQ / MQ)), dim3(NTH), 0, stream>>>(q, k, v, out);
}